// Round 4
// baseline (6345.684 us; speedup 1.0000x reference)
//
#include <hip/hip_runtime.h>

#define CIN  32
#define COUT 64
#define KK   27
#define EPSV 1e-5f

// ---------- conv1: feats[N,32] gather-GEMM -> t1[N,64] ----------
__global__ __launch_bounds__(256) void k_conv1(
    const float* __restrict__ feats, const int* __restrict__ nbr,
    const float* __restrict__ W, float* __restrict__ t1, int n)
{
    int p  = blockIdx.x * 256 + threadIdx.x;
    int pc = p < n ? p : n - 1;
    float acc[COUT];
#pragma unroll
    for (int c = 0; c < COUT; c++) acc[c] = 0.f;
    const int* np = nbr + pc * KK;
#pragma unroll 1
    for (int k = 0; k < KK; k++) {
        int idx = np[k];
        const float4* fr = (const float4*)(feats + idx * CIN);
        float f[CIN];
#pragma unroll
        for (int q = 0; q < CIN / 4; q++) {
            float4 v = fr[q];
            f[4*q+0] = v.x; f[4*q+1] = v.y; f[4*q+2] = v.z; f[4*q+3] = v.w;
        }
        const float* Wk = W + k * (CIN * COUT);
#pragma unroll 4
        for (int j = 0; j < CIN; j++) {
            float fj = f[j];
            const float* wr = Wk + j * COUT;   // wave-uniform -> s_load
#pragma unroll
            for (int c = 0; c < COUT; c++) acc[c] = fmaf(fj, wr[c], acc[c]);
        }
    }
    if (p < n) {
        float4* o = (float4*)(t1 + p * COUT);
#pragma unroll
        for (int q = 0; q < COUT / 4; q++)
            o[q] = make_float4(acc[4*q], acc[4*q+1], acc[4*q+2], acc[4*q+3]);
    }
}

// ---------- per-channel sum / sumsq of an [n,64] fp32 array ----------
__global__ __launch_bounds__(256) void k_sum(const float* __restrict__ x, int n,
                                             float* __restrict__ S)
{
    __shared__ float ls[2 * COUT];
    if (threadIdx.x < 2 * COUT) ls[threadIdx.x] = 0.f;
    __syncthreads();
    long long total4 = (long long)n * (COUT / 4);
    long long stride = (long long)gridDim.x * 256;
    float s0 = 0, s1 = 0, s2 = 0, s3 = 0, q0 = 0, q1 = 0, q2 = 0, q3 = 0;
    for (long long i = (long long)blockIdx.x * 256 + threadIdx.x; i < total4; i += stride) {
        float4 v = ((const float4*)x)[i];
        s0 += v.x; q0 += v.x * v.x;
        s1 += v.y; q1 += v.y * v.y;
        s2 += v.z; q2 += v.z * v.z;
        s3 += v.w; q3 += v.w * v.w;
    }
    // gridDim.x*256*4 is a multiple of 64 -> each thread's channel set is fixed
    int cb = (threadIdx.x * 4) & (COUT - 1);
    atomicAdd(&ls[cb + 0], s0); atomicAdd(&ls[cb + 1], s1);
    atomicAdd(&ls[cb + 2], s2); atomicAdd(&ls[cb + 3], s3);
    atomicAdd(&ls[COUT + cb + 0], q0); atomicAdd(&ls[COUT + cb + 1], q1);
    atomicAdd(&ls[COUT + cb + 2], q2); atomicAdd(&ls[COUT + cb + 3], q3);
    __syncthreads();
    if (threadIdx.x < 2 * COUT) atomicAdd(&S[threadIdx.x], ls[threadIdx.x]);
}

// ---------- conv2: gather t1, fused bn1+relu on gathered rows -> t2[N,64] ----------
__global__ __launch_bounds__(256) void k_conv2(
    const float* __restrict__ t1, const int* __restrict__ nbr,
    const float* __restrict__ W, const float* __restrict__ S,
    const float* __restrict__ g, const float* __restrict__ b,
    float* __restrict__ t2, int n, float invn)
{
    __shared__ float sA[COUT], sB[COUT];
    if (threadIdx.x < COUT) {
        int c = threadIdx.x;
        float mu  = S[c] * invn;
        float var = fmaxf(S[COUT + c] * invn - mu * mu, 0.f);
        float a   = g[c] * rsqrtf(var + EPSV);
        sA[c] = a; sB[c] = b[c] - mu * a;
    }
    __syncthreads();
    int p  = blockIdx.x * 256 + threadIdx.x;
    int pc = p < n ? p : n - 1;
    float acc[COUT];
#pragma unroll
    for (int c = 0; c < COUT; c++) acc[c] = 0.f;
    const int* np = nbr + pc * KK;
#pragma unroll 1
    for (int k = 0; k < KK; k++) {
        int idx = np[k];
        const float4* fr = (const float4*)(t1 + idx * COUT);
        float f[COUT];
#pragma unroll
        for (int q = 0; q < COUT / 4; q++) {
            float4 v = fr[q];
            f[4*q+0] = v.x; f[4*q+1] = v.y; f[4*q+2] = v.z; f[4*q+3] = v.w;
        }
#pragma unroll
        for (int j = 0; j < COUT; j++)
            f[j] = fmaxf(fmaf(f[j], sA[j], sB[j]), 0.f);  // bn1+relu on the fly
        const float* Wk = W + k * (COUT * COUT);
#pragma unroll 4
        for (int j = 0; j < COUT; j++) {
            float fj = f[j];
            const float* wr = Wk + j * COUT;   // wave-uniform -> s_load
#pragma unroll
            for (int c = 0; c < COUT; c++) acc[c] = fmaf(fj, wr[c], acc[c]);
        }
    }
    if (p < n) {
        float4* o = (float4*)(t2 + p * COUT);
#pragma unroll
        for (int q = 0; q < COUT / 4; q++)
            o[q] = make_float4(acc[4*q], acc[4*q+1], acc[4*q+2], acc[4*q+3]);
    }
}

// ---------- x0 = relu(bn2(t2)) + feats@Wlin -> x0f[N,64] fp32 ----------
__global__ __launch_bounds__(256) void k_x0(
    const float* __restrict__ t2, const float* __restrict__ feats,
    const float* __restrict__ S, const float* __restrict__ g, const float* __restrict__ b,
    const float* __restrict__ Wlin, float* __restrict__ x0f, int n, float invn)
{
    __shared__ float sA[COUT], sB[COUT];
    if (threadIdx.x < COUT) {
        int c = threadIdx.x;
        float mu  = S[c] * invn;
        float var = fmaxf(S[COUT + c] * invn - mu * mu, 0.f);
        float a   = g[c] * rsqrtf(var + EPSV);
        sA[c] = a; sB[c] = b[c] - mu * a;
    }
    __syncthreads();
    int p  = blockIdx.x * 256 + threadIdx.x;
    int pc = p < n ? p : n - 1;
    float f[CIN];
    {
        const float4* fr = (const float4*)(feats + pc * CIN);
#pragma unroll
        for (int q = 0; q < CIN / 4; q++) {
            float4 v = fr[q];
            f[4*q+0] = v.x; f[4*q+1] = v.y; f[4*q+2] = v.z; f[4*q+3] = v.w;
        }
    }
    float acc[COUT];
    {
        const float4* tr = (const float4*)(t2 + pc * COUT);
#pragma unroll
        for (int q = 0; q < COUT / 4; q++) {
            float4 v = tr[q];
            acc[4*q+0] = fmaxf(fmaf(v.x, sA[4*q+0], sB[4*q+0]), 0.f);
            acc[4*q+1] = fmaxf(fmaf(v.y, sA[4*q+1], sB[4*q+1]), 0.f);
            acc[4*q+2] = fmaxf(fmaf(v.z, sA[4*q+2], sB[4*q+2]), 0.f);
            acc[4*q+3] = fmaxf(fmaf(v.w, sA[4*q+3], sB[4*q+3]), 0.f);
        }
    }
#pragma unroll 4
    for (int j = 0; j < CIN; j++) {
        float fj = f[j];
        const float* wr = Wlin + j * COUT;     // wave-uniform -> s_load
#pragma unroll
        for (int c = 0; c < COUT; c++) acc[c] = fmaf(fj, wr[c], acc[c]);
    }
    if (p < n) {
        float4* o = (float4*)(x0f + p * COUT);
#pragma unroll
        for (int q = 0; q < COUT / 4; q++)
            o[q] = make_float4(acc[4*q], acc[4*q+1], acc[4*q+2], acc[4*q+3]);
    }
}

// ---------- pool: y = mean over 27 gathered fp32 rows ----------
__global__ __launch_bounds__(256) void k_pool(
    const float* __restrict__ x, const int* __restrict__ nbr,
    float* __restrict__ y, int n)
{
    int p  = blockIdx.x * 256 + threadIdx.x;
    int pc = p < n ? p : n - 1;
    float acc[COUT];
#pragma unroll
    for (int c = 0; c < COUT; c++) acc[c] = 0.f;
    const int* np = nbr + pc * KK;
#pragma unroll 3
    for (int k = 0; k < KK; k++) {
        int idx = np[k];
        const float4* r = (const float4*)(x + idx * COUT);
#pragma unroll
        for (int q = 0; q < COUT / 4; q++) {
            float4 v = r[q];
            acc[4*q+0] += v.x; acc[4*q+1] += v.y;
            acc[4*q+2] += v.z; acc[4*q+3] += v.w;
        }
    }
    if (p < n) {
        const float inv = 1.f / 27.f;
        float4* o = (float4*)(y + p * COUT);
#pragma unroll
        for (int q = 0; q < COUT / 4; q++)
            o[q] = make_float4(acc[4*q]*inv, acc[4*q+1]*inv, acc[4*q+2]*inv, acc[4*q+3]*inv);
    }
}

// ---------- final: x3=pool(x2,nbr9); gates=x0@Wsw; out = s0*x0 + s1*(x1*g0+x2*g1+x3*g2) ----------
// block = 192 threads; x0 row per thread staged in LDS (stride 65 -> conflict-free)
__global__ __launch_bounds__(192) void k_final(
    const float* __restrict__ x0f, const float* __restrict__ x1f,
    const float* __restrict__ x2f, const int* __restrict__ nbr,
    const float* __restrict__ Wsw, const float* __restrict__ sc0,
    const float* __restrict__ sc1, float* __restrict__ out, int n)
{
    __shared__ float xs[192 * 65];
    int p  = blockIdx.x * 192 + threadIdx.x;
    int pc = p < n ? p : n - 1;
    float* myx = xs + threadIdx.x * 65;
    {
        const float4* xr = (const float4*)(x0f + pc * COUT);
#pragma unroll
        for (int q = 0; q < COUT / 4; q++) {
            float4 v = xr[q];
            myx[4*q+0] = v.x; myx[4*q+1] = v.y; myx[4*q+2] = v.z; myx[4*q+3] = v.w;
        }
    }
    int idx[KK];
#pragma unroll
    for (int k = 0; k < KK; k++) idx[k] = nbr[pc * KK + k];
    const float inv27 = 1.f / 27.f;

#pragma unroll 1
    for (int ch = 0; ch < 4; ch++) {
        int cb = ch * 16;
        float g0[16], g1[16], g2[16];
#pragma unroll
        for (int i = 0; i < 16; i++) { g0[i] = 0.f; g1[i] = 0.f; g2[i] = 0.f; }
#pragma unroll 1
        for (int j = 0; j < COUT; j++) {
            float fj = myx[j];                    // LDS, conflict-free
            const float* wr = Wsw + j * 192 + cb; // wave-uniform -> s_load
#pragma unroll
            for (int cc = 0; cc < 16; cc++) {
                g0[cc] = fmaf(fj, wr[cc],        g0[cc]);
                g1[cc] = fmaf(fj, wr[64 + cc],   g1[cc]);
                g2[cc] = fmaf(fj, wr[128 + cc],  g2[cc]);
            }
        }
        float x3[16];
#pragma unroll
        for (int i = 0; i < 16; i++) x3[i] = 0.f;
#pragma unroll 1
        for (int k = 0; k < KK; k++) {
            const float4* r = (const float4*)(x2f + idx[k] * COUT + cb);
#pragma unroll
            for (int q = 0; q < 4; q++) {
                float4 v = r[q];
                x3[4*q+0] += v.x; x3[4*q+1] += v.y;
                x3[4*q+2] += v.z; x3[4*q+3] += v.w;
            }
        }
        if (p < n) {
            const float4* r1 = (const float4*)(x1f + pc * COUT + cb);
            const float4* r2 = (const float4*)(x2f + pc * COUT + cb);
            float x1v[16], x2v[16];
#pragma unroll
            for (int q = 0; q < 4; q++) {
                float4 a = r1[q];
                x1v[4*q+0] = a.x; x1v[4*q+1] = a.y; x1v[4*q+2] = a.z; x1v[4*q+3] = a.w;
                float4 b = r2[q];
                x2v[4*q+0] = b.x; x2v[4*q+1] = b.y; x2v[4*q+2] = b.z; x2v[4*q+3] = b.w;
            }
            float ov[16];
#pragma unroll
            for (int cc = 0; cc < 16; cc++) {
                float f2 = x1v[cc] * g0[cc] + x2v[cc] * g1[cc] + (x3[cc] * inv27) * g2[cc];
                ov[cc] = sc0[cb + cc] * myx[cb + cc] + sc1[cb + cc] * f2;
            }
            float4* o = (float4*)(out + p * COUT + cb);
#pragma unroll
            for (int q = 0; q < 4; q++)
                o[q] = make_float4(ov[4*q], ov[4*q+1], ov[4*q+2], ov[4*q+3]);
        }
    }
}

extern "C" void kernel_launch(void* const* d_in, const int* in_sizes, int n_in,
                              void* d_out, int out_size, void* d_ws, size_t ws_size,
                              hipStream_t stream)
{
    const float* feats = (const float*)d_in[0];
    const int*   nbr1  = (const int*)d_in[1];
    const int*   nbr3  = (const int*)d_in[2];
    const int*   nbr9  = (const int*)d_in[3];
    const float* W0a   = (const float*)d_in[4];
    const float* g1    = (const float*)d_in[5];
    const float* b1    = (const float*)d_in[6];
    const float* W0b   = (const float*)d_in[7];
    const float* g2    = (const float*)d_in[8];
    const float* b2    = (const float*)d_in[9];
    const float* Wlin  = (const float*)d_in[10];
    const float* Wsw   = (const float*)d_in[11];
    const float* sc0   = (const float*)d_in[12];
    const float* sc1   = (const float*)d_in[13];

    int n = in_sizes[0] / CIN;   // 400000
    float* base = (float*)d_ws;
    // buffer A: t1 then x0f | buffer B: t2 then x1 | buffer C: x2 | S: stats
    float* A = base;
    float* B = base + (size_t)n * COUT;
    float* C = base + (size_t)2 * n * COUT;
    float* S = base + (size_t)3 * n * COUT;
    float* out = (float*)d_out;
    float invn = 1.0f / (float)n;

    int grid  = (n + 255) / 256;
    int gridF = (n + 191) / 192;

    hipMemsetAsync(S, 0, 256 * sizeof(float), stream);
    k_conv1<<<grid, 256, 0, stream>>>(feats, nbr1, W0a, A, n);
    k_sum<<<2048, 256, 0, stream>>>(A, n, S);
    k_conv2<<<grid, 256, 0, stream>>>(A, nbr1, W0b, S, g1, b1, B, n, invn);
    k_sum<<<2048, 256, 0, stream>>>(B, n, S + 128);
    k_x0<<<grid, 256, 0, stream>>>(B, feats, S + 128, g2, b2, Wlin, A, n, invn);
    k_pool<<<grid, 256, 0, stream>>>(A, nbr1, B, n);
    k_pool<<<grid, 256, 0, stream>>>(B, nbr3, C, n);
    k_final<<<gridF, 192, 0, stream>>>(A, B, C, nbr9, Wsw, sc0, sc1, out, n);
}